// Round 12
// baseline (263.011 us; speedup 1.0000x reference)
//
#include <hip/hip_runtime.h>

#define HW 129600
#define WG 360
#define HG 360
#define NCLS 10
#define NPROP 200
#define CDIM 128
#define NROWS 80000
#define NB 2
#define NPB (NROWS / NB)    // rows are batch-sorted: row<40000 -> b=0
#define SEL_CAP 4096
#define HBINS 4096          // heat in (0,1]: (bits>>18) <= 4064
#define RPB 64              // rows per k_head block
#define PSTR 12             // row stride (floats): 10 classes + 2 pad, 48B
#define BPB 32              // k_sel blocks per batch (emit parallelism)

// 48B all-zero row for invalid NMS neighbors: lives in module .rodata,
// never touched by workspace poisoning. No memset needed.
__device__ __align__(16) const float ZROW[12] = {0.f, 0.f, 0.f, 0.f, 0.f, 0.f,
                                                 0.f, 0.f, 0.f, 0.f, 0.f, 0.f};

// ---------------------------------------------------------------------------
// Async global->LDS DMA, 16B per lane; LDS dest wave-uniform base (m97/m104).
// ---------------------------------------------------------------------------
__device__ __forceinline__ void lds_cp16(float* l, const float* g) {
  __builtin_amdgcn_global_load_lds(
      (const __attribute__((address_space(1))) void*)g,
      (__attribute__((address_space(3))) void*)l, 16, 0, 0);
}

__device__ __forceinline__ float4 fmax4(float4 a, float4 b) {
  float4 r;
  r.x = fmaxf(a.x, b.x);
  r.y = fmaxf(a.y, b.y);
  r.z = fmaxf(a.z, b.z);
  r.w = fmaxf(a.w, b.w);
  return r;
}

// ---------------------------------------------------------------------------
// K1: fused MLP head (R11 verbatim — triple-buffered K-loop, counted vmcnt,
// prefetch distance 2; proven 63->59us, VALUBusy 70%). Block 0 zeroes hist.
// ---------------------------------------------------------------------------
__global__ __launch_bounds__(256, 4) void k_head(
    const float* __restrict__ feat, const float* __restrict__ W1,
    const float* __restrict__ b1, const float* __restrict__ W2,
    const float* __restrict__ b2, const int* __restrict__ idxs,
    float* __restrict__ val_raw, int* __restrict__ rowmap,
    unsigned int* __restrict__ hist) {
  __shared__ __align__(16) float lds_w[3][16 * 128];  // 24KB: W1 chunks
  __shared__ __align__(16) float lds_f[3][RPB * 16];  // 12KB: f chunks
  const int tid = threadIdx.x;
  const int row0 = blockIdx.x * RPB;
  const int tc = tid & 31;
  const int tr = tid >> 5;
  const int wv = tid >> 6;  // wave id (uniform within wave)
  const int lane = tid & 63;

  auto stage = [&](int kt, int nb) {  // 3 global_load_lds per thread
#pragma unroll
    for (int c = 0; c < 2; ++c) {
      const int off = (wv * 2 + c) * 256;  // wave-uniform float offset
      lds_cp16(&lds_w[nb][off], W1 + kt * 2048 + off + lane * 4);
    }
    {
      const int off = wv * 256;
      const int fidx = off + lane * 4;
      const int r = fidx >> 4, kk = fidx & 15;
      lds_cp16(&lds_f[nb][off],
               feat + (size_t)(row0 + r) * CDIM + kt * 16 + kk);
    }
  };

  stage(0, 0);
  stage(1, 1);  // prefetch distance 2
  if (blockIdx.x == 0) {  // replaces hist memset dispatch
    uint4* h4 = (uint4*)hist;
    for (int i = tid; i < (NB * HBINS) / 4; i += 256)
      h4[i] = make_uint4(0u, 0u, 0u, 0u);
  }
  if (tid < RPB) {
    int row = row0 + tid;
    int bb = idxs[row * 3 + 0];
    int yy = idxs[row * 3 + 1];
    int xx = idxs[row * 3 + 2];
    rowmap[(size_t)bb * HW + yy * WG + xx] = row;
  }

  float acc[8][4];
#pragma unroll
  for (int r = 0; r < 8; ++r)
#pragma unroll
    for (int c = 0; c < 4; ++c) acc[r][c] = 0.f;

#pragma unroll
  for (int kt = 0; kt < 8; ++kt) {
    const int cb = kt % 3;
    // wait the consumed buffer's 3 loads (oldest); keep the rest in flight
    if (kt < 7) {
      asm volatile("s_waitcnt vmcnt(3)" ::: "memory");
    } else {
      asm volatile("s_waitcnt vmcnt(0)" ::: "memory");
    }
    __builtin_amdgcn_sched_barrier(0);
    __builtin_amdgcn_s_barrier();  // publish all waves' DMA; free buf (kt-1)%3
    __builtin_amdgcn_sched_barrier(0);
    if (kt < 6) stage(kt + 2, (kt + 2) % 3);  // WAR-safe: after barrier
#pragma unroll
    for (int kg = 0; kg < 4; ++kg) {
      float4 w0 = *(const float4*)(&lds_w[cb][(kg * 4 + 0) * 128 + tc * 4]);
      float4 w1 = *(const float4*)(&lds_w[cb][(kg * 4 + 1) * 128 + tc * 4]);
      float4 w2 = *(const float4*)(&lds_w[cb][(kg * 4 + 2) * 128 + tc * 4]);
      float4 w3 = *(const float4*)(&lds_w[cb][(kg * 4 + 3) * 128 + tc * 4]);
#pragma unroll
      for (int r = 0; r < 8; ++r) {
        float4 fv = *(const float4*)(&lds_f[cb][(tr * 8 + r) * 16 + kg * 4]);
        acc[r][0] = fmaf(fv.x, w0.x, acc[r][0]);
        acc[r][0] = fmaf(fv.y, w1.x, acc[r][0]);
        acc[r][0] = fmaf(fv.z, w2.x, acc[r][0]);
        acc[r][0] = fmaf(fv.w, w3.x, acc[r][0]);
        acc[r][1] = fmaf(fv.x, w0.y, acc[r][1]);
        acc[r][1] = fmaf(fv.y, w1.y, acc[r][1]);
        acc[r][1] = fmaf(fv.z, w2.y, acc[r][1]);
        acc[r][1] = fmaf(fv.w, w3.y, acc[r][1]);
        acc[r][2] = fmaf(fv.x, w0.z, acc[r][2]);
        acc[r][2] = fmaf(fv.y, w1.z, acc[r][2]);
        acc[r][2] = fmaf(fv.z, w2.z, acc[r][2]);
        acc[r][2] = fmaf(fv.w, w3.z, acc[r][2]);
        acc[r][3] = fmaf(fv.x, w0.w, acc[r][3]);
        acc[r][3] = fmaf(fv.y, w1.w, acc[r][3]);
        acc[r][3] = fmaf(fv.z, w2.w, acc[r][3]);
        acc[r][3] = fmaf(fv.w, w3.w, acc[r][3]);
      }
    }
  }
  __syncthreads();  // all compute done before epilogue reuses buffers

  // stage W2^T into lds_f[0] (1280 floats <= 3072 available)
  float* w2t = &lds_f[0][0];
  for (int i = tid; i < CDIM * NCLS; i += 256) {
    int k = i / NCLS, j = i - k * NCLS;
    w2t[j * 128 + k] = W2[i];
  }
  __syncthreads();

  // ---- layer 2, two 32-row halves through hbuf = lds_w[0..] (16KB) ----
  float* hbuf = &lds_w[0][0];  // 4096 floats needed <= 6144 available
  float4 b1v = *(const float4*)(b1 + tc * 4);
#pragma unroll
  for (int half = 0; half < 2; ++half) {
    if ((tr >> 2) == half) {  // wave-uniform: waves 0,1 = half0; 2,3 = half1
      int ltr = tr & 3;
#pragma unroll
      for (int r = 0; r < 8; ++r) {
        float4 h;
        h.x = fmaxf(acc[r][0] + b1v.x, 0.f);
        h.y = fmaxf(acc[r][1] + b1v.y, 0.f);
        h.z = fmaxf(acc[r][2] + b1v.z, 0.f);
        h.w = fmaxf(acc[r][3] + b1v.w, 0.f);
        *(float4*)(hbuf + (ltr * 8 + r) * 128 + tc * 4) = h;
      }
    }
    __syncthreads();
    for (int o = tid; o < 32 * NCLS; o += 256) {
      int r = o / NCLS, j = o - r * NCLS;
      float s = b2[j];
      for (int i4 = 0; i4 < 32; ++i4) {
        int k4 = (i4 + tid) & 31;
        float4 hv = *(const float4*)(hbuf + r * 128 + k4 * 4);
        float4 wv2 = *(const float4*)(w2t + j * 128 + k4 * 4);
        s = fmaf(hv.x, wv2.x, s);
        s = fmaf(hv.y, wv2.y, s);
        s = fmaf(hv.z, wv2.z, s);
        s = fmaf(hv.w, wv2.w, s);
      }
      float heat = 1.0f / (1.0f + expf(-s));
      int gr = half * 32 + r;
      val_raw[(size_t)(row0 + gr) * PSTR + j] = heat;  // compact, coalesced
    }
    __syncthreads();
  }
}

// ---------------------------------------------------------------------------
// K2: sparse NMS + histogram via VALIDATED rowmap indirection (R5/R11
// verbatim — the proven-best NMS; fusion refuted twice at R6/R10).
// ---------------------------------------------------------------------------
__global__ __launch_bounds__(256) void k_nms(
    const float* __restrict__ val_raw, const int* __restrict__ idxs,
    const int* __restrict__ rowmap, float* __restrict__ val,
    unsigned int* __restrict__ hist) {
  __shared__ unsigned int lh[HBINS];
  const int tid = threadIdx.x;
  const int row = blockIdx.x * 256 + tid;
  const int blk_b = (blockIdx.x * 256 >= NPB) ? 1 : 0;
  for (int i = tid; i < HBINS; i += 256) lh[i] = 0;
  __syncthreads();

  float v[10];
  int bb = 0;
  const bool valid = row < NROWS;
  if (valid) {
    bb = (row >= NPB) ? 1 : 0;
    const int y = idxs[row * 3 + 1];
    const int x = idxs[row * 3 + 2];
    const int pos = y * WG + x;
    const float* cbase = val_raw + (size_t)row * PSTR;
    float4 c0 = *(const float4*)(cbase + 0);
    float4 c1 = *(const float4*)(cbase + 4);
    float2 c89 = *(const float2*)(cbase + 8);
    const bool interior = (y > 0 && y < HG - 1 && x > 0 && x < WG - 1);
    if (interior) {
      const int dyA[8] = {0, 0, -1, -1, -1, 1, 1, 1};
      const int dxA[8] = {-1, 1, -1, 0, 1, -1, 0, 1};
      float4 m0 = c0, m1 = c1;
      const int* rmb = rowmap + (size_t)bb * HW + pos;
#pragma unroll
      for (int n = 0; n < 8; ++n) {
        const int nrow = rmb[dyA[n] * WG + dxA[n]];
        bool ok =
            ((unsigned)nrow < NROWS) && ((nrow >= NPB) == (bb == 1));
        if (ok) {
          ok = (idxs[nrow * 3 + 1] == y + dyA[n]) &&
               (idxs[nrow * 3 + 2] == x + dxA[n]);
        }
        const float* p = ok ? (val_raw + (size_t)nrow * PSTR) : ZROW;
        m0 = fmax4(m0, *(const float4*)(p + 0));
        m1 = fmax4(m1, *(const float4*)(p + 4));
      }
      v[0] = (c0.x == m0.x) ? c0.x : 0.f;
      v[1] = (c0.y == m0.y) ? c0.y : 0.f;
      v[2] = (c0.z == m0.z) ? c0.z : 0.f;
      v[3] = (c0.w == m0.w) ? c0.w : 0.f;
      v[4] = (c1.x == m1.x) ? c1.x : 0.f;
      v[5] = (c1.y == m1.y) ? c1.y : 0.f;
      v[6] = (c1.z == m1.z) ? c1.z : 0.f;
      v[7] = (c1.w == m1.w) ? c1.w : 0.f;
    } else {
      v[0] = v[1] = v[2] = v[3] = v[4] = v[5] = v[6] = v[7] = 0.f;
    }
    v[8] = c89.x;
    v[9] = c89.y;
    // store suppressed vals (stride 12, 16B-aligned)
    float4 s0 = {v[0], v[1], v[2], v[3]};
    float4 s1 = {v[4], v[5], v[6], v[7]};
    float4 s2 = {v[8], v[9], 0.f, 0.f};
    *(float4*)(val + (size_t)row * PSTR + 0) = s0;
    *(float4*)(val + (size_t)row * PSTR + 4) = s1;
    *(float4*)(val + (size_t)row * PSTR + 8) = s2;
#pragma unroll
    for (int c = 0; c < 10; ++c) {
      if (v[c] > 0.f) {
        unsigned int bin = __float_as_uint(v[c]) >> 18;
        if (bb == blk_b)
          atomicAdd(&lh[bin], 1u);
        else  // only the batch-straddling block takes this path
          atomicAdd(&hist[(size_t)bb * HBINS + bin], 1u);
      }
    }
  }
  __syncthreads();
  unsigned int* gh = hist + (size_t)blk_b * HBINS;
  for (int i = tid; i < HBINS; i += 256) {
    unsigned int c = lh[i];
    if (c) atomicAdd(&gh[i], c);
  }
}

// ---------------------------------------------------------------------------
// K3 (NEW, replaces k_collect+k_final — one fewer device-wide handoff):
// 64 blocks (32/batch). Each block: threshold from global hist (verbatim
// suffix-scan math) -> scans its OWN batch's val (1.92MB, L2-resident,
// sequential) collecting passing keys into LDS via one block-local counter
// (no sel buffer, no global atomics) -> exact top-200 by rank-counting ->
// partitioned emit. Same T, same keys, same cap semantics -> bit-exact.
// ---------------------------------------------------------------------------
__global__ __launch_bounds__(256) void k_sel(
    const float* __restrict__ val, const int* __restrict__ idxs,
    const unsigned int* __restrict__ hist, const int* __restrict__ rowmap,
    const float* __restrict__ feat, const float* __restrict__ Wc,
    const float* __restrict__ bc, float* __restrict__ out) {
  __shared__ unsigned long long sk[SEL_CAP];  // 32KB
  __shared__ unsigned long long winners[NPROP];
  __shared__ int wcls[NPROP];
  __shared__ int wrow[NPROP];
  __shared__ unsigned int coarse[256];
  __shared__ unsigned int fine16[16];
  __shared__ int sT1, sCi1, lcnt;
  const int b = blockIdx.x / BPB;
  const int part = blockIdx.x % BPB;
  const int tid = threadIdx.x;

  // ---- threshold for batch b (math verbatim from the old k_collect) ----
  if (tid == 0) {
    sCi1 = -1;
    sT1 = 0;
    lcnt = 0;
  }
  {
    const unsigned int* h = hist + (size_t)b * HBINS;
    const uint4* h4 = (const uint4*)(h + tid * 16);
    unsigned int s = 0;
#pragma unroll
    for (int i = 0; i < 4; ++i) {
      uint4 q = h4[i];
      s += q.x + q.y + q.z + q.w;
    }
    coarse[tid] = s;
  }
  __syncthreads();
  // in-place suffix scan: coarse[t] = sum_{i>=t} coarse_orig[i]
#pragma unroll
  for (int off = 1; off < 256; off <<= 1) {
    unsigned int vv = (tid + off < 256) ? coarse[tid + off] : 0u;
    __syncthreads();
    coarse[tid] += vv;
    __syncthreads();
  }
  if (coarse[tid] >= NPROP) atomicMax(&sCi1, tid);
  __syncthreads();
  {
    const int ci = sCi1;  // block-uniform (read after barrier)
    if (ci >= 0) {
      if (tid < 16) fine16[tid] = hist[(size_t)b * HBINS + ci * 16 + tid];
      __syncthreads();
      if (tid == 0) {
        unsigned int cum = (ci + 1 < 256) ? coarse[ci + 1] : 0u;
        int t = 15;
        for (; t > 0; --t) {
          unsigned int c = fine16[t];
          if (cum + c >= NPROP) break;
          cum += c;
        }
        sT1 = ci * 16 + t;
      }
    }
    __syncthreads();
  }
  const int T = sT1;

  // ---- collect: sequential scan of this batch's val (L2-resident) ----
  for (int r = tid; r < NPB; r += 256) {
    const int row = b * NPB + r;
    float4 a0 = *(const float4*)(val + (size_t)row * PSTR + 0);
    float4 a1 = *(const float4*)(val + (size_t)row * PSTR + 4);
    float2 a2 = *(const float2*)(val + (size_t)row * PSTR + 8);
    const float v[10] = {a0.x, a0.y, a0.z, a0.w, a1.x,
                         a1.y, a1.z, a1.w, a2.x, a2.y};
    const int pos = idxs[row * 3 + 1] * WG + idxs[row * 3 + 2];
#pragma unroll
    for (int cl = 0; cl < 10; ++cl) {
      unsigned int bits = __float_as_uint(v[cl]);
      if (v[cl] > 0.f && (int)(bits >> 18) >= T) {
        int ls = atomicAdd(&lcnt, 1);  // LDS, block-local (~400 total)
        if (ls < SEL_CAP) {
          unsigned int gidx = (unsigned int)cl * HW + (unsigned int)pos;
          // key: heat bits desc, then smaller gidx (jax top_k tie-break)
          sk[ls] =
              ((unsigned long long)bits << 32) | (unsigned long long)(~gidx);
        }
      }
    }
  }
  __syncthreads();
  int M = lcnt;
  if (M > SEL_CAP) M = SEL_CAP;

  // ---- exact top-200 by rank-counting (keys unique) ----
  for (int i = tid; i < M; i += 256) {
    unsigned long long key = sk[i];
    int rank = 0;
    for (int j = 0; j < M; ++j) rank += (sk[j] > key) ? 1 : 0;
    if (rank < NPROP) winners[rank] = key;
  }
  __syncthreads();
  if (tid < NPROP) {
    unsigned long long key = winners[tid];
    unsigned int gidx = ~((unsigned int)(key & 0xFFFFFFFFull));
    int cls = (int)(gidx / HW);
    int pos = (int)(gidx - (unsigned int)cls * HW);
    wcls[tid] = cls;
    wrow[tid] = rowmap[(size_t)b * HW + pos];
    if (part == 0) {
      int y = pos / WG, x = pos - y * WG;
      out[51200 + ((size_t)b * NPROP + tid) * 2 + 0] = (float)x;
      out[51200 + ((size_t)b * NPROP + tid) * 2 + 1] = (float)y;
      out[56000 + b * NPROP + tid] = (float)cls;
    }
  }
  __syncthreads();
  // qhs (B, NCLS, NPROP) at 52000 — partitioned strided slices
  for (int o = part * 256 + tid; o < NCLS * NPROP; o += BPB * 256) {
    int j = o / NPROP, pp = o - j * NPROP;
    out[52000 + (size_t)b * NCLS * NPROP + o] = val[(size_t)wrow[pp] * PSTR + j];
  }
  // qf (B, C, NPROP) at 0 — partitioned strided slices
  for (int o = part * 256 + tid; o < CDIM * NPROP; o += BPB * 256) {
    int c = o / NPROP, pp = o - c * NPROP;
    out[(size_t)b * CDIM * NPROP + o] =
        feat[(size_t)wrow[pp] * CDIM + c] + Wc[c * NCLS + wcls[pp]] + bc[c];
  }
}

// ---------------------------------------------------------------------------
// ws layout (bytes) — NO memsets; hist zeroed by k_head block 0, rowmap is
// validation-checked (no init), ZROW is module .rodata; sel/sel_cnt GONE:
//   [0)        hist    : B*4096*4 = 32,768
//   [32768)    rowmap  : B*HW*4   = 1,036,800   -> 1,069,568
//   [1069568)  val_raw : 80000*12*4 = 3,840,000 -> 4,909,568
//   [4909568)  val     : 80000*12*4 = 3,840,000 -> 8,749,568
// total ~8.75 MB. Dispatches: 3 (one fewer device-wide handoff than R11).
// ---------------------------------------------------------------------------
extern "C" void kernel_launch(void* const* d_in, const int* in_sizes, int n_in,
                              void* d_out, int out_size, void* d_ws,
                              size_t ws_size, hipStream_t stream) {
  const float* feat = (const float*)d_in[0];
  const float* W1 = (const float*)d_in[1];
  const float* b1 = (const float*)d_in[2];
  const float* W2 = (const float*)d_in[3];
  const float* b2 = (const float*)d_in[4];
  const float* Wc = (const float*)d_in[5];
  const float* bc = (const float*)d_in[6];
  const int* idxs = (const int*)d_in[7];
  float* out = (float*)d_out;

  char* ws = (char*)d_ws;
  unsigned int* hist = (unsigned int*)(ws + 0);
  int* rowmap = (int*)(ws + 32768);
  float* val_raw = (float*)(ws + 1069568);
  float* val = (float*)(ws + 4909568);

  k_head<<<NROWS / RPB, 256, 0, stream>>>(feat, W1, b1, W2, b2, idxs, val_raw,
                                          rowmap, hist);
  k_nms<<<(NROWS + 255) / 256, 256, 0, stream>>>(val_raw, idxs, rowmap, val,
                                                 hist);
  k_sel<<<NB * BPB, 256, 0, stream>>>(val, idxs, hist, rowmap, feat, Wc, bc,
                                      out);
}

// Round 13
// 180.091 us; speedup vs baseline: 1.4604x; 1.4604x over previous
//
#include <hip/hip_runtime.h>

#define HW 129600
#define WG 360
#define HG 360
#define NCLS 10
#define NPROP 200
#define CDIM 128
#define NROWS 80000
#define NB 2
#define NPB (NROWS / NB)    // rows are batch-sorted: row<40000 -> b=0
#define SEL_CAP 4096
#define HBINS 4096          // heat in (0,1]: (bits>>18) <= 4064
#define RPB 128             // rows per k_head block (8x8 per-thread tile)
#define PSTR 12             // row stride (floats): 10 classes + 2 pad, 48B
#define BPB 32              // k_final blocks per batch (emit parallelism)

// 48B all-zero row for invalid NMS neighbors: lives in module .rodata,
// never touched by workspace poisoning. No memset needed.
__device__ __align__(16) const float ZROW[12] = {0.f, 0.f, 0.f, 0.f, 0.f, 0.f,
                                                 0.f, 0.f, 0.f, 0.f, 0.f, 0.f};

// ---------------------------------------------------------------------------
// Async global->LDS DMA, 16B per lane; LDS dest wave-uniform base (m97/m104).
// ---------------------------------------------------------------------------
__device__ __forceinline__ void lds_cp16(float* l, const float* g) {
  __builtin_amdgcn_global_load_lds(
      (const __attribute__((address_space(1))) void*)g,
      (__attribute__((address_space(3))) void*)l, 16, 0, 0);
}

__device__ __forceinline__ float4 fmax4(float4 a, float4 b) {
  float4 r;
  r.x = fmaxf(a.x, b.x);
  r.y = fmaxf(a.y, b.y);
  r.z = fmaxf(a.z, b.z);
  r.w = fmaxf(a.w, b.w);
  return r;
}

// ---------------------------------------------------------------------------
// K1: fused MLP head. NEW vs R11: RPB 128, per-thread tile 8 rows x 8 cols
// (acc[8][8]) -> 2x FMA per LDS byte (R11 was LDS-BW-limited at ~25us floor
// vs FMA 16.7us; measured 59us). Triple-buffered K-loop with counted
// vmcnt(4) (4 loads/stage now), prefetch distance 2 — R11-proven pattern.
// Per-element FMA k-order unchanged (kt*16+kg*4+{0..3}, fv.x..fv.w) and
// layer-2 keeps the exact tid<->(r,j)<->k4-rotation mapping per 32-row
// quarter -> heat bit-exact. Block 0 zeroes hist + sel_cnt.
// ---------------------------------------------------------------------------
__global__ __launch_bounds__(256, 3) void k_head(
    const float* __restrict__ feat, const float* __restrict__ W1,
    const float* __restrict__ b1, const float* __restrict__ W2,
    const float* __restrict__ b2, const int* __restrict__ idxs,
    float* __restrict__ val_raw, int* __restrict__ rowmap,
    unsigned int* __restrict__ hist, int* __restrict__ sel_cnt) {
  __shared__ __align__(16) float lds_w[3][16 * 128];   // 24KB: W1 chunks
  __shared__ __align__(16) float lds_f[3][RPB * 16];   // 24KB: f chunks
  const int tid = threadIdx.x;
  const int row0 = blockIdx.x * RPB;
  const int tc = tid & 15;   // col group: cols tc*8 .. tc*8+7
  const int tr = tid >> 4;   // row group: rows tr*8 .. tr*8+7
  const int wv = tid >> 6;   // wave id (uniform within wave)
  const int lane = tid & 63;

  auto stage = [&](int kt, int nb) {  // 4 global_load_lds per thread
#pragma unroll
    for (int c = 0; c < 2; ++c) {
      const int off = (wv * 2 + c) * 256;  // wave-uniform float offset
      lds_cp16(&lds_w[nb][off], W1 + kt * 2048 + off + lane * 4);
    }
#pragma unroll
    for (int c = 0; c < 2; ++c) {
      const int off = (wv * 2 + c) * 256;
      const int fidx = off + lane * 4;
      const int r = fidx >> 4, kk = fidx & 15;
      lds_cp16(&lds_f[nb][off],
               feat + (size_t)(row0 + r) * CDIM + kt * 16 + kk);
    }
  };

  stage(0, 0);
  stage(1, 1);  // prefetch distance 2
  if (blockIdx.x == 0) {  // replaces hist/sel_cnt memset dispatches
    uint4* h4 = (uint4*)hist;
    for (int i = tid; i < (NB * HBINS) / 4; i += 256)
      h4[i] = make_uint4(0u, 0u, 0u, 0u);
    if (tid < 2) sel_cnt[tid] = 0;
  }
  if (tid < RPB) {
    int row = row0 + tid;
    int bb = idxs[row * 3 + 0];
    int yy = idxs[row * 3 + 1];
    int xx = idxs[row * 3 + 2];
    rowmap[(size_t)bb * HW + yy * WG + xx] = row;
  }

  float acc[8][8];
#pragma unroll
  for (int r = 0; r < 8; ++r)
#pragma unroll
    for (int c = 0; c < 8; ++c) acc[r][c] = 0.f;

#pragma unroll
  for (int kt = 0; kt < 8; ++kt) {
    const int cb = kt % 3;
    // wait the consumed buffer's 4 loads (oldest); keep the rest in flight
    if (kt < 7) {
      asm volatile("s_waitcnt vmcnt(4)" ::: "memory");
    } else {
      asm volatile("s_waitcnt vmcnt(0)" ::: "memory");
    }
    __builtin_amdgcn_sched_barrier(0);
    __builtin_amdgcn_s_barrier();  // publish all waves' DMA; free buf (kt-1)%3
    __builtin_amdgcn_sched_barrier(0);
    if (kt < 6) stage(kt + 2, (kt + 2) % 3);  // WAR-safe: after barrier
#pragma unroll
    for (int kg = 0; kg < 4; ++kg) {
      // cols tc*8..tc*8+3 (A) and tc*8+4..tc*8+7 (B), k rows kg*4+{0..3}
      float4 a0 = *(const float4*)(&lds_w[cb][(kg * 4 + 0) * 128 + tc * 8]);
      float4 a1 = *(const float4*)(&lds_w[cb][(kg * 4 + 1) * 128 + tc * 8]);
      float4 a2 = *(const float4*)(&lds_w[cb][(kg * 4 + 2) * 128 + tc * 8]);
      float4 a3 = *(const float4*)(&lds_w[cb][(kg * 4 + 3) * 128 + tc * 8]);
      float4 b0 = *(const float4*)(&lds_w[cb][(kg * 4 + 0) * 128 + tc * 8 + 4]);
      float4 b1q = *(const float4*)(&lds_w[cb][(kg * 4 + 1) * 128 + tc * 8 + 4]);
      float4 b2q = *(const float4*)(&lds_w[cb][(kg * 4 + 2) * 128 + tc * 8 + 4]);
      float4 b3q = *(const float4*)(&lds_w[cb][(kg * 4 + 3) * 128 + tc * 8 + 4]);
#pragma unroll
      for (int r = 0; r < 8; ++r) {
        float4 fv = *(const float4*)(&lds_f[cb][(tr * 8 + r) * 16 + kg * 4]);
        acc[r][0] = fmaf(fv.x, a0.x, acc[r][0]);
        acc[r][0] = fmaf(fv.y, a1.x, acc[r][0]);
        acc[r][0] = fmaf(fv.z, a2.x, acc[r][0]);
        acc[r][0] = fmaf(fv.w, a3.x, acc[r][0]);
        acc[r][1] = fmaf(fv.x, a0.y, acc[r][1]);
        acc[r][1] = fmaf(fv.y, a1.y, acc[r][1]);
        acc[r][1] = fmaf(fv.z, a2.y, acc[r][1]);
        acc[r][1] = fmaf(fv.w, a3.y, acc[r][1]);
        acc[r][2] = fmaf(fv.x, a0.z, acc[r][2]);
        acc[r][2] = fmaf(fv.y, a1.z, acc[r][2]);
        acc[r][2] = fmaf(fv.z, a2.z, acc[r][2]);
        acc[r][2] = fmaf(fv.w, a3.z, acc[r][2]);
        acc[r][3] = fmaf(fv.x, a0.w, acc[r][3]);
        acc[r][3] = fmaf(fv.y, a1.w, acc[r][3]);
        acc[r][3] = fmaf(fv.z, a2.w, acc[r][3]);
        acc[r][3] = fmaf(fv.w, a3.w, acc[r][3]);
        acc[r][4] = fmaf(fv.x, b0.x, acc[r][4]);
        acc[r][4] = fmaf(fv.y, b1q.x, acc[r][4]);
        acc[r][4] = fmaf(fv.z, b2q.x, acc[r][4]);
        acc[r][4] = fmaf(fv.w, b3q.x, acc[r][4]);
        acc[r][5] = fmaf(fv.x, b0.y, acc[r][5]);
        acc[r][5] = fmaf(fv.y, b1q.y, acc[r][5]);
        acc[r][5] = fmaf(fv.z, b2q.y, acc[r][5]);
        acc[r][5] = fmaf(fv.w, b3q.y, acc[r][5]);
        acc[r][6] = fmaf(fv.x, b0.z, acc[r][6]);
        acc[r][6] = fmaf(fv.y, b1q.z, acc[r][6]);
        acc[r][6] = fmaf(fv.z, b2q.z, acc[r][6]);
        acc[r][6] = fmaf(fv.w, b3q.z, acc[r][6]);
        acc[r][7] = fmaf(fv.x, b0.w, acc[r][7]);
        acc[r][7] = fmaf(fv.y, b1q.w, acc[r][7]);
        acc[r][7] = fmaf(fv.z, b2q.w, acc[r][7]);
        acc[r][7] = fmaf(fv.w, b3q.w, acc[r][7]);
      }
    }
  }
  __syncthreads();  // all compute done before epilogue reuses buffers

  // stage W2^T into lds_f[0] (1280 floats <= 6144 available)
  float* w2t = &lds_f[0][0];
  for (int i = tid; i < CDIM * NCLS; i += 256) {
    int k = i / NCLS, j = i - k * NCLS;
    w2t[j * 128 + k] = W2[i];
  }
  __syncthreads();

  // ---- layer 2: four 32-row quarters through hbuf = lds_w (16KB) ----
  float* hbuf = &lds_w[0][0];  // 4096 floats needed <= 6144 available
  float4 b1a = *(const float4*)(b1 + tc * 8);
  float4 b1b = *(const float4*)(b1 + tc * 8 + 4);
#pragma unroll
  for (int q = 0; q < 4; ++q) {
    if ((tr >> 2) == q) {  // wave-uniform: wave q owns quarter q
      int ltr = tr & 3;
#pragma unroll
      for (int r = 0; r < 8; ++r) {
        float4 h;
        h.x = fmaxf(acc[r][0] + b1a.x, 0.f);
        h.y = fmaxf(acc[r][1] + b1a.y, 0.f);
        h.z = fmaxf(acc[r][2] + b1a.z, 0.f);
        h.w = fmaxf(acc[r][3] + b1a.w, 0.f);
        *(float4*)(hbuf + (ltr * 8 + r) * 128 + tc * 8) = h;
        float4 h2;
        h2.x = fmaxf(acc[r][4] + b1b.x, 0.f);
        h2.y = fmaxf(acc[r][5] + b1b.y, 0.f);
        h2.z = fmaxf(acc[r][6] + b1b.z, 0.f);
        h2.w = fmaxf(acc[r][7] + b1b.w, 0.f);
        *(float4*)(hbuf + (ltr * 8 + r) * 128 + tc * 8 + 4) = h2;
      }
    }
    __syncthreads();
    for (int o = tid; o < 32 * NCLS; o += 256) {
      int r = o / NCLS, j = o - r * NCLS;
      float s = b2[j];
      for (int i4 = 0; i4 < 32; ++i4) {
        int k4 = (i4 + tid) & 31;
        float4 hv = *(const float4*)(hbuf + r * 128 + k4 * 4);
        float4 wv2 = *(const float4*)(w2t + j * 128 + k4 * 4);
        s = fmaf(hv.x, wv2.x, s);
        s = fmaf(hv.y, wv2.y, s);
        s = fmaf(hv.z, wv2.z, s);
        s = fmaf(hv.w, wv2.w, s);
      }
      float heat = 1.0f / (1.0f + expf(-s));
      int gr = q * 32 + r;
      val_raw[(size_t)(row0 + gr) * PSTR + j] = heat;  // compact, coalesced
    }
    __syncthreads();
  }
}

// ---------------------------------------------------------------------------
// K2: sparse NMS + histogram via VALIDATED rowmap indirection (R11 verbatim).
// ---------------------------------------------------------------------------
__global__ __launch_bounds__(256) void k_hist(
    const float* __restrict__ val_raw, const int* __restrict__ idxs,
    const int* __restrict__ rowmap, float* __restrict__ val,
    unsigned int* __restrict__ hist) {
  __shared__ unsigned int lh[HBINS];
  const int tid = threadIdx.x;
  const int row = blockIdx.x * 256 + tid;
  const int blk_b = (blockIdx.x * 256 >= NPB) ? 1 : 0;
  for (int i = tid; i < HBINS; i += 256) lh[i] = 0;
  __syncthreads();

  float v[10];
  int bb = 0;
  const bool valid = row < NROWS;
  if (valid) {
    bb = (row >= NPB) ? 1 : 0;
    const int y = idxs[row * 3 + 1];
    const int x = idxs[row * 3 + 2];
    const int pos = y * WG + x;
    const float* cbase = val_raw + (size_t)row * PSTR;
    float4 c0 = *(const float4*)(cbase + 0);
    float4 c1 = *(const float4*)(cbase + 4);
    float2 c89 = *(const float2*)(cbase + 8);
    const bool interior = (y > 0 && y < HG - 1 && x > 0 && x < WG - 1);
    if (interior) {
      const int dyA[8] = {0, 0, -1, -1, -1, 1, 1, 1};
      const int dxA[8] = {-1, 1, -1, 0, 1, -1, 0, 1};
      float4 m0 = c0, m1 = c1;
      const int* rmb = rowmap + (size_t)bb * HW + pos;
#pragma unroll
      for (int n = 0; n < 8; ++n) {
        const int nrow = rmb[dyA[n] * WG + dxA[n]];
        bool ok =
            ((unsigned)nrow < NROWS) && ((nrow >= NPB) == (bb == 1));
        if (ok) {
          ok = (idxs[nrow * 3 + 1] == y + dyA[n]) &&
               (idxs[nrow * 3 + 2] == x + dxA[n]);
        }
        const float* p = ok ? (val_raw + (size_t)nrow * PSTR) : ZROW;
        m0 = fmax4(m0, *(const float4*)(p + 0));
        m1 = fmax4(m1, *(const float4*)(p + 4));
      }
      v[0] = (c0.x == m0.x) ? c0.x : 0.f;
      v[1] = (c0.y == m0.y) ? c0.y : 0.f;
      v[2] = (c0.z == m0.z) ? c0.z : 0.f;
      v[3] = (c0.w == m0.w) ? c0.w : 0.f;
      v[4] = (c1.x == m1.x) ? c1.x : 0.f;
      v[5] = (c1.y == m1.y) ? c1.y : 0.f;
      v[6] = (c1.z == m1.z) ? c1.z : 0.f;
      v[7] = (c1.w == m1.w) ? c1.w : 0.f;
    } else {
      v[0] = v[1] = v[2] = v[3] = v[4] = v[5] = v[6] = v[7] = 0.f;
    }
    v[8] = c89.x;
    v[9] = c89.y;
    // store suppressed vals (stride 12, 16B-aligned)
    float4 s0 = {v[0], v[1], v[2], v[3]};
    float4 s1 = {v[4], v[5], v[6], v[7]};
    float4 s2 = {v[8], v[9], 0.f, 0.f};
    *(float4*)(val + (size_t)row * PSTR + 0) = s0;
    *(float4*)(val + (size_t)row * PSTR + 4) = s1;
    *(float4*)(val + (size_t)row * PSTR + 8) = s2;
#pragma unroll
    for (int c = 0; c < 10; ++c) {
      if (v[c] > 0.f) {
        unsigned int bin = __float_as_uint(v[c]) >> 18;
        if (bb == blk_b)
          atomicAdd(&lh[bin], 1u);
        else  // only the batch-straddling block takes this path
          atomicAdd(&hist[(size_t)bb * HBINS + bin], 1u);
      }
    }
  }
  __syncthreads();
  unsigned int* gh = hist + (size_t)blk_b * HBINS;
  for (int i = tid; i < HBINS; i += 256) {
    unsigned int c = lh[i];
    if (c) atomicAdd(&gh[i], c);
  }
}

// ---------------------------------------------------------------------------
// K3: per-block threshold via parallel suffix-scan + compaction (R11 verbatim).
// ---------------------------------------------------------------------------
__global__ __launch_bounds__(256) void k_collect(
    const float* __restrict__ val, const int* __restrict__ idxs,
    const unsigned int* __restrict__ hist, unsigned long long* __restrict__ sel,
    int* __restrict__ sel_cnt) {
  __shared__ unsigned int coarse[256];
  __shared__ unsigned int fine16[16];
  __shared__ int sT[2];
  __shared__ int sCi[2];
  const int tid = threadIdx.x;
  for (int bb = 0; bb < NB; ++bb) {
    const unsigned int* h = hist + (size_t)bb * HBINS;
    const uint4* h4 = (const uint4*)(h + tid * 16);
    unsigned int s = 0;
#pragma unroll
    for (int i = 0; i < 4; ++i) {
      uint4 q = h4[i];
      s += q.x + q.y + q.z + q.w;
    }
    if (tid == 0) {
      sCi[bb] = -1;
      sT[bb] = 0;
    }
    coarse[tid] = s;
    __syncthreads();
    // in-place suffix scan: coarse[t] = sum_{i>=t} coarse_orig[i]
#pragma unroll
    for (int off = 1; off < 256; off <<= 1) {
      unsigned int vv = (tid + off < 256) ? coarse[tid + off] : 0u;
      __syncthreads();
      coarse[tid] += vv;
      __syncthreads();
    }
    if (coarse[tid] >= NPROP) atomicMax(&sCi[bb], tid);
    __syncthreads();
    const int ci = sCi[bb];
    if (ci >= 0) {
      if (tid < 16) fine16[tid] = h[ci * 16 + tid];
      __syncthreads();
      if (tid == 0) {
        unsigned int cum = (ci + 1 < 256) ? coarse[ci + 1] : 0u;
        int t = 15;
        for (; t > 0; --t) {
          unsigned int c = fine16[t];
          if (cum + c >= NPROP) break;
          cum += c;
        }
        sT[bb] = ci * 16 + t;
      }
    }
    __syncthreads();
  }
  const int row = blockIdx.x * 256 + tid;
  const bool valid = row < NROWS;
  const int bb = (valid && row >= NPB) ? 1 : 0;
  const int T = sT[bb];
  float v[12];
  int pos = 0;
  if (valid) {
    *(float4*)(v + 0) = *(const float4*)(val + (size_t)row * PSTR + 0);
    *(float4*)(v + 4) = *(const float4*)(val + (size_t)row * PSTR + 4);
    *(float4*)(v + 8) = *(const float4*)(val + (size_t)row * PSTR + 8);
    pos = idxs[row * 3 + 1] * WG + idxs[row * 3 + 2];
  }
  const int lane = tid & 63;
#pragma unroll
  for (int cl = 0; cl < 10; ++cl) {
    float vv = valid ? v[cl] : 0.f;
    unsigned int bits = __float_as_uint(vv);
    bool pred = (vv > 0.f) && ((int)(bits >> 18) >= T);
    unsigned long long m0 = __ballot(pred && (bb == 0));
    unsigned long long m1 = __ballot(pred && (bb == 1));
    if (pred) {
      unsigned long long mask = bb ? m1 : m0;
      int leader = __ffsll((unsigned long long)mask) - 1;
      int lb = __popcll(mask & ((1ull << lane) - 1ull));
      int base = 0;
      if (lane == leader) base = atomicAdd(&sel_cnt[bb], (int)__popcll(mask));
      base = __shfl(base, leader, 64);
      unsigned int gidx = (unsigned int)cl * HW + (unsigned int)pos;
      // key: heat bits desc, then smaller gidx first (jax top_k tie-break)
      unsigned long long key =
          ((unsigned long long)bits << 32) | (unsigned long long)(~gidx);
      int slot = base + lb;
      if (slot < SEL_CAP) sel[(size_t)bb * SEL_CAP + slot] = key;
    }
  }
}

// ---------------------------------------------------------------------------
// K4: exact top-200 by rank-counting, 32 blocks/batch partitioned emit
// (R11 verbatim).
// ---------------------------------------------------------------------------
__global__ __launch_bounds__(256) void k_final(
    const unsigned long long* __restrict__ sel, const int* __restrict__ sel_cnt,
    const float* __restrict__ val, const int* __restrict__ rowmap,
    const float* __restrict__ feat, const float* __restrict__ Wc,
    const float* __restrict__ bc, float* __restrict__ out) {
  __shared__ unsigned long long sk[SEL_CAP];
  __shared__ unsigned long long winners[NPROP];
  __shared__ int wcls[NPROP];
  __shared__ int wrow[NPROP];
  const int b = blockIdx.x / BPB;
  const int part = blockIdx.x % BPB;
  const int tid = threadIdx.x;
  int M = sel_cnt[b];
  if (M > SEL_CAP) M = SEL_CAP;
  for (int i = tid; i < M; i += 256) sk[i] = sel[(size_t)b * SEL_CAP + i];
  __syncthreads();
  for (int i = tid; i < M; i += 256) {
    unsigned long long key = sk[i];
    int rank = 0;
    for (int j = 0; j < M; ++j) rank += (sk[j] > key) ? 1 : 0;
    if (rank < NPROP) winners[rank] = key;
  }
  __syncthreads();
  if (tid < NPROP) {
    unsigned long long key = winners[tid];
    unsigned int gidx = ~((unsigned int)(key & 0xFFFFFFFFull));
    int cls = (int)(gidx / HW);
    int pos = (int)(gidx - (unsigned int)cls * HW);
    wcls[tid] = cls;
    wrow[tid] = rowmap[(size_t)b * HW + pos];
    if (part == 0) {
      int y = pos / WG, x = pos - y * WG;
      out[51200 + ((size_t)b * NPROP + tid) * 2 + 0] = (float)x;
      out[51200 + ((size_t)b * NPROP + tid) * 2 + 1] = (float)y;
      out[56000 + b * NPROP + tid] = (float)cls;
    }
  }
  __syncthreads();
  // qhs (B, NCLS, NPROP) at 52000 — partitioned strided slices
  for (int o = part * 256 + tid; o < NCLS * NPROP; o += BPB * 256) {
    int j = o / NPROP, pp = o - j * NPROP;
    out[52000 + (size_t)b * NCLS * NPROP + o] = val[(size_t)wrow[pp] * PSTR + j];
  }
  // qf (B, C, NPROP) at 0 — partitioned strided slices
  for (int o = part * 256 + tid; o < CDIM * NPROP; o += BPB * 256) {
    int c = o / NPROP, pp = o - c * NPROP;
    out[(size_t)b * CDIM * NPROP + o] =
        feat[(size_t)wrow[pp] * CDIM + c] + Wc[c * NCLS + wcls[pp]] + bc[c];
  }
}

// ---------------------------------------------------------------------------
// ws layout (bytes) — NO memsets; hist/sel_cnt zeroed by k_head block 0,
// rowmap is validation-checked (no init), ZROW is module .rodata:
//   [0)        hist    : B*4096*4 = 32,768
//   [32768)    rowmap  : B*HW*4   = 1,036,800  -> ends 1,069,568
//   [1069568)  sel     : B*4096*8 = 65,536     -> ends 1,135,104
//   [1135104)  cnts    : sel_cnt[2] (16B)      -> 1,135,120
//   [1135120)  val_raw : 80000*12*4 = 3,840,000 -> 4,975,120
//   [4975120)  val     : 80000*12*4 = 3,840,000 -> 8,815,120
// total ~8.8 MB. Dispatches: 4 (R11 tail verbatim; fusion refuted 3x).
// ---------------------------------------------------------------------------
extern "C" void kernel_launch(void* const* d_in, const int* in_sizes, int n_in,
                              void* d_out, int out_size, void* d_ws,
                              size_t ws_size, hipStream_t stream) {
  const float* feat = (const float*)d_in[0];
  const float* W1 = (const float*)d_in[1];
  const float* b1 = (const float*)d_in[2];
  const float* W2 = (const float*)d_in[3];
  const float* b2 = (const float*)d_in[4];
  const float* Wc = (const float*)d_in[5];
  const float* bc = (const float*)d_in[6];
  const int* idxs = (const int*)d_in[7];
  float* out = (float*)d_out;

  char* ws = (char*)d_ws;
  unsigned int* hist = (unsigned int*)(ws + 0);
  int* rowmap = (int*)(ws + 32768);
  unsigned long long* sel = (unsigned long long*)(ws + 1069568);
  int* sel_cnt = (int*)(ws + 1135104);
  float* val_raw = (float*)(ws + 1135120);
  float* val = (float*)(ws + 4975120);

  k_head<<<NROWS / RPB, 256, 0, stream>>>(feat, W1, b1, W2, b2, idxs, val_raw,
                                          rowmap, hist, sel_cnt);
  k_hist<<<(NROWS + 255) / 256, 256, 0, stream>>>(val_raw, idxs, rowmap, val,
                                                  hist);
  k_collect<<<(NROWS + 255) / 256, 256, 0, stream>>>(val, idxs, hist, sel,
                                                     sel_cnt);
  k_final<<<NB * BPB, 256, 0, stream>>>(sel, sel_cnt, val, rowmap, feat, Wc, bc,
                                        out);
}